// Round 6
// baseline (149.917 us; speedup 1.0000x reference)
//
#include <hip/hip_runtime.h>
#include <hip/hip_bf16.h>
#include <math.h>

// N_AGENTS=16, RNN_H=64, N_HEADS=4, GAT_D=32, EMB=32, SDIM=128, B=4096 rows

typedef __attribute__((ext_vector_type(8))) short short8;
typedef __attribute__((ext_vector_type(8))) unsigned short ushort8;
typedef __attribute__((ext_vector_type(4))) float float4v;
typedef __attribute__((ext_vector_type(4))) _Float16 half4v;

static __device__ inline unsigned short f2bf(float f) {
    unsigned int x;
    __builtin_memcpy(&x, &f, 4);
    unsigned int r = x + 0x7fffu + ((x >> 16) & 1u);   // RNE
    return (unsigned short)(r >> 16);
}

// packed f32x2 -> bf16x2 (v_cvt_pk_bf16_f32, RNE)
static __device__ inline unsigned int cvtpk(float lo, float hi) {
    __hip_bfloat162 h = __float22bfloat162_rn(make_float2(lo, hi));
    unsigned int u;
    __builtin_memcpy(&u, &h, 4);
    return u;
}

static __device__ inline short8 pack8(float4 f0, float4 f1) {
    unsigned int u[4] = {cvtpk(f0.x, f0.y), cvtpk(f0.z, f0.w),
                         cvtpk(f1.x, f1.y), cvtpk(f1.z, f1.w)};
    short8 s;
    __builtin_memcpy(&s, u, 16);
    return s;
}

// ---------------------------------------------------------------------------
// Launch 1: w1s_W -> w1sTf FRAG-MAJOR bf16 pack only (the one true producer).
// 256 blocks, one 16-col tile each; LDS transpose; coalesced frag stores.
// ---------------------------------------------------------------------------
__global__ __launch_bounds__(256) void k0_pack(
    const float* __restrict__ w1s_W,     // [129][4096]
    unsigned short* __restrict__ w1sTf)  // [256 tiles][2048] bf16 frag-major
{
    __shared__ __align__(16) unsigned short T[16 * 136];
    const int tid = threadIdx.x, bx = blockIdx.x;
    const int c0 = bx * 16;
    const int cc = tid & 15, kr = tid >> 4;
    #pragma unroll
    for (int t = 0; t < 8; ++t) {
        int k = t * 16 + kr;
        T[cc * 136 + k] = f2bf(w1s_W[(size_t)k * 4096 + c0 + cc]);
    }
    __syncthreads();
    const int ks = tid >> 6, q = (tid >> 4) & 3, mm = tid & 15;
    *(ushort8*)&w1sTf[(size_t)bx * 2048 + tid * 8] =
        *(const ushort8*)&T[mm * 136 + ks * 32 + q * 8];
}

// ---------------------------------------------------------------------------
// Launch 2 (kB): three INDEPENDENT block families.
//  blocks 0..63    : MFMA GEMVs -> b1v, wfv, out = v (direct-global B-frags)
//  block 64        : W_gat -> WgTf frag-major (9 tiles + fused attn proj)
//  blocks 65..2112 : streaming GEMM W2 (fix+bias fused), A-frags = vector
//                    16B loads from w1sTf, B-frags packed in-wave from
//                    states (row-contiguous float4). 1 wave = 1 E x 64 rows.
// Static LDS 18432B -> 8 blocks/CU.
// ---------------------------------------------------------------------------
__global__ __launch_bounds__(256) void kB_fused(
    const float* __restrict__ w1s_W,     // [129][4096] (row 128 for fix)
    const float* __restrict__ W_gat,     // [64][128]
    const float* __restrict__ att_a,     // [4][64]
    const float* __restrict__ states,    // [4096][128]
    const float* __restrict__ uncertainty, // [4096]
    const float* __restrict__ w1s_b,
    const unsigned short* __restrict__ w1sTf, // [256][2048] frag-major
    const float* __restrict__ b1_W, const float* __restrict__ b1_b,
    const float* __restrict__ wf_W, const float* __restrict__ wf_b,
    const float* __restrict__ V1_W, const float* __restrict__ V1_b,
    const float* __restrict__ V2_W, const float* __restrict__ V2_b,
    unsigned short* __restrict__ WgTf,   // [9 tiles][1024] bf16 frag-major
    unsigned short* __restrict__ W2,     // [4096 r][4096 c'] bf16
    float* __restrict__ b1v, float* __restrict__ wfv,
    float* __restrict__ out)             // seeded with v
{
    __shared__ __align__(16) unsigned short T[128 * 72];   // 18432 B (block 64)
    const int tid = threadIdx.x, bx = blockIdx.x;
    const int wave = tid >> 6, lane = tid & 63;
    const int m = lane & 15, quad = lane >> 4;

    if (bx < 64) {
        // ---- MFMA GEMV block: 64 rows, 4 waves x 16 rows ----
        const int b0w = bx * 64 + wave * 16;

        short8 a[4];
        #pragma unroll
        for (int ks = 0; ks < 4; ++ks) {
            const float* sp = states + (size_t)(b0w + m) * 128 + ks * 32 + quad * 8;
            a[ks] = pack8(*(const float4*)sp, *(const float4*)(sp + 4));
        }
        float4v accT[6];
        #pragma unroll
        for (int nt = 0; nt < 6; ++nt) accT[nt] = (float4v){0.f, 0.f, 0.f, 0.f};
        #pragma unroll
        for (int nt = 0; nt < 6; ++nt) {
            const float* Wset = (nt < 2) ? b1_W : (nt < 4 ? wf_W : V1_W);
            const int e = (nt & 1) * 16 + m;
            #pragma unroll
            for (int ks = 0; ks < 4; ++ks) {
                unsigned int u[4];
                #pragma unroll
                for (int jp = 0; jp < 4; ++jp) {
                    float g0 = Wset[(ks * 32 + quad * 8 + 2 * jp) * 32 + e];
                    float g1 = Wset[(ks * 32 + quad * 8 + 2 * jp + 1) * 32 + e];
                    u[jp] = cvtpk(g0, g1);
                }
                short8 bf;
                __builtin_memcpy(&bf, u, 16);
                accT[nt] = __builtin_amdgcn_mfma_f32_16x16x32_bf16(a[ks], bf, accT[nt], 0, 0, 0);
            }
        }
        float vsum[4] = {0.f, 0.f, 0.f, 0.f};
        #pragma unroll
        for (int p = 0; p < 2; ++p) {
            const int e = p * 16 + m;
            const float bb1 = b1_b[e], bwf = wf_b[e], bv1 = V1_b[e], v2 = V2_W[e];
            #pragma unroll
            for (int reg = 0; reg < 4; ++reg) {
                const int row = b0w + quad * 4 + reg;
                b1v[(size_t)row * 32 + e] = accT[p][reg] + bb1;
                wfv[(size_t)row * 32 + e] = fabsf(accT[2 + p][reg] + bwf);
                vsum[reg] += fmaxf(accT[4 + p][reg] + bv1, 0.f) * v2;
            }
        }
        #pragma unroll
        for (int reg = 0; reg < 4; ++reg) {
            vsum[reg] += __shfl_xor(vsum[reg], 1);
            vsum[reg] += __shfl_xor(vsum[reg], 2);
            vsum[reg] += __shfl_xor(vsum[reg], 4);
            vsum[reg] += __shfl_xor(vsum[reg], 8);
        }
        if (m == 0) {
            #pragma unroll
            for (int reg = 0; reg < 4; ++reg)
                out[b0w + quad * 4 + reg] = vsum[reg] + V2_b[0];
        }
    } else if (bx == 64) {
        // ---- WgTf builder ----
        #pragma unroll
        for (int t = 0; t < 32; ++t) {
            int i = t * 256 + tid;
            int k = i >> 7, c = i & 127;
            T[c * 72 + k] = f2bf(W_gat[k * 128 + c]);
        }
        __syncthreads();
        #pragma unroll
        for (int t = 0; t < 4; ++t) {
            int i = t * 256 + tid;            // < 1024 ushort8 groups
            int nt = i >> 7, w = i & 127;
            int kh = w >> 6, q = (w >> 4) & 3, mm = w & 15;
            *(ushort8*)&WgTf[nt * 1024 + w * 8] =
                *(const ushort8*)&T[(nt * 16 + mm) * 72 + kh * 32 + q * 8];
        }
        // tile 8: fused attention projections (m = h: src, m = 4+h: dst)
        {
            const int k = tid >> 2, h = tid & 3;
            float ss = 0.f, dd = 0.f;
            #pragma unroll
            for (int d = 0; d < 32; ++d) {
                float wv = W_gat[k * 128 + h * 32 + d];
                ss = fmaf(wv, att_a[h * 64 + d], ss);
                dd = fmaf(wv, att_a[h * 64 + 32 + d], dd);
            }
            const int base = 8192 + (k >> 5) * 512 + ((k >> 3) & 3) * 128 + (k & 7);
            WgTf[base + h * 8]       = f2bf(ss);
            WgTf[base + (4 + h) * 8] = f2bf(dd);
        }
        #pragma unroll
        for (int t = 0; t < 2; ++t) {         // zero cols m = 8..15
            int i = t * 256 + tid;            // < 512
            int kh = i >> 8, q2 = (i >> 6) & 3, mm = 8 + ((i >> 3) & 7), j = i & 7;
            WgTf[8192 + kh * 512 + q2 * 128 + mm * 8 + j] = 0;
        }
    } else {
        // ---- streaming GEMM block: 4 waves = 4 E's, 64 rows ----
        const int gb = bx - 65;
        const int rb = gb >> 5, pg = gb & 31;   // 64 row-blocks, 32 col-groups
        const int E = pg * 4 + wave;            // [0,128)
        const int ct0 = E * 2;                  // tiles: d<16, d>=16

        const float* w128 = w1s_W + (size_t)128 * 4096;

        // A-frags: vector 16B loads from pre-packed w1sTf
        short8 A[2][4];
        #pragma unroll
        for (int t = 0; t < 2; ++t)
            #pragma unroll
            for (int ks = 0; ks < 4; ++ks)
                A[t][ks] = *(const short8*)&w1sTf[(size_t)(ct0 + t) * 2048 + ks * 512 + lane * 8];

        float wf[2][4], bb[2][4];
        #pragma unroll
        for (int t = 0; t < 2; ++t) {
            float4 w4 = *(const float4*)&w128[(ct0 + t) * 16 + quad * 4];
            float4 b4 = *(const float4*)&w1s_b[(ct0 + t) * 16 + quad * 4];
            wf[t][0] = w4.x; wf[t][1] = w4.y; wf[t][2] = w4.z; wf[t][3] = w4.w;
            bb[t][0] = b4.x; bb[t][1] = b4.y; bb[t][2] = b4.z; bb[t][3] = b4.w;
        }

        const int eo = (E >> 4) * 512 + (E & 15) * 32 + quad * 8;

        #pragma unroll
        for (int c = 0; c < 4; ++c) {
            const int r0c = rb * 64 + c * 16;
            const float us = uncertainty[r0c + m];   // lane's row = m
            // B-frags packed in-wave from row-contiguous states (vector loads)
            short8 Bf[4];
            #pragma unroll
            for (int ks = 0; ks < 4; ++ks) {
                const float* sp = states + (size_t)(r0c + m) * 128 + ks * 32 + quad * 8;
                Bf[ks] = pack8(*(const float4*)sp, *(const float4*)(sp + 4));
            }

            float4v z0 = (float4v){0.f, 0.f, 0.f, 0.f};
            float4v z1 = (float4v){0.f, 0.f, 0.f, 0.f};
            #pragma unroll
            for (int ks = 0; ks < 4; ++ks) {
                z0 = __builtin_amdgcn_mfma_f32_16x16x32_bf16(A[0][ks], Bf[ks], z0, 0, 0, 0);
                z1 = __builtin_amdgcn_mfma_f32_16x16x32_bf16(A[1][ks], Bf[ks], z1, 0, 0, 0);
            }
            unsigned int wpk[4];
            #pragma unroll
            for (int reg = 0; reg < 4; ++reg) {
                float za = z0[reg] + us * wf[0][reg] + bb[0][reg];
                float zb = z1[reg] + us * wf[1][reg] + bb[1][reg];
                wpk[reg] = cvtpk(za, zb);            // d' = (2d, 2d+1)
            }
            short8 pk;
            __builtin_memcpy(&pk, wpk, 16);
            *(short8*)&W2[(size_t)(r0c + m) * 4096 + eo] = pk;
        }
    }
}

// ---------------------------------------------------------------------------
// Launch 3: GAT + contraction + epilogue fused, 1 wave = 1 batch row.
// (round-3 form + s_setprio around MFMA clusters)
// ---------------------------------------------------------------------------
__global__ __launch_bounds__(256) void k1_gatmix(
    const float* __restrict__ hidden_states,  // [4096*16][64] fp32
    const unsigned short* __restrict__ WgTf,  // [9][1024] bf16 frag-major
    const unsigned short* __restrict__ W2,    // [4096][4096] bf16 frag-major
    const float* __restrict__ agent_qs,       // [4096][16]
    const float* __restrict__ b1v, const float* __restrict__ wfv,
    float* __restrict__ out)                  // seeded with v
{
    const int wave = threadIdx.x >> 6;
    const int b = blockIdx.x * 4 + wave;
    const int lane = threadIdx.x & 63, m = lane & 15, quad = lane >> 4;
    __shared__ __align__(16) float sc[4 * 320];   // per-wave scratch, 5KB
    float* scr = &sc[wave * 320];

    // prefetch W2 A-frags (i = h*2+H), hidden under GAT compute
    short8 wfr[8];
    #pragma unroll
    for (int i = 0; i < 8; ++i)
        wfr[i] = *(const short8*)&W2[(size_t)b * 4096 + i * 512 + m * 32 + quad * 8];
    const float qs_m = agent_qs[b * 16 + m];

    // ---- MFMA1: 8 hp tiles + proj tile ----
    const float* hrow = hidden_states + ((size_t)b * 16 + m) * 64;
    float4 f0 = *(const float4*)(hrow + quad * 8);
    float4 f1 = *(const float4*)(hrow + quad * 8 + 4);
    short8 a0 = pack8(f0, f1);
    f0 = *(const float4*)(hrow + 32 + quad * 8);
    f1 = *(const float4*)(hrow + 32 + quad * 8 + 4);
    short8 a1 = pack8(f0, f1);

    float4v hpt[9];
    __builtin_amdgcn_s_setprio(1);
    #pragma unroll
    for (int nt = 0; nt < 9; ++nt) {
        short8 bf0 = *(const short8*)&WgTf[nt * 1024 + lane * 8];
        short8 bf1 = *(const short8*)&WgTf[nt * 1024 + 512 + lane * 8];
        float4v z = (float4v){0.f, 0.f, 0.f, 0.f};
        z = __builtin_amdgcn_mfma_f32_16x16x32_bf16(a0, bf0, z, 0, 0, 0);
        z = __builtin_amdgcn_mfma_f32_16x16x32_bf16(a1, bf1, z, 0, 0, 0);
        hpt[nt] = z;
    }
    __builtin_amdgcn_s_setprio(0);

    // stash proj tile transposed: scr[col*20 + row]
    {
        float4 pr = {hpt[8][0], hpt[8][1], hpt[8][2], hpt[8][3]};
        *(float4*)&scr[m * 20 + quad * 4] = pr;
    }

    float Sacc[2][4] = {};

    // ---- per head: softmax + PV MFMA + in-register contraction ----
    #pragma unroll
    for (int h = 0; h < 4; ++h) {
        const float src_m = scr[h * 20 + m];                        // src[i=m]
        float4 pdv = *(const float4*)&scr[(4 + h) * 20 + quad * 4]; // dst[j]
        float pd[4] = {pdv.x, pdv.y, pdv.z, pdv.w};

        float e_[4];
        #pragma unroll
        for (int jj = 0; jj < 4; ++jj) {
            float x = src_m + pd[jj];
            e_[jj] = fmaxf(x, 0.2f * x);       // leaky_relu(0.2)
        }
        float mx = fmaxf(fmaxf(e_[0], e_[1]), fmaxf(e_[2], e_[3]));
        mx = fmaxf(mx, __shfl_xor(mx, 16));
        mx = fmaxf(mx, __shfl_xor(mx, 32));
        float p_[4], ssum = 0.f;
        #pragma unroll
        for (int jj = 0; jj < 4; ++jj) { p_[jj] = __expf(e_[jj] - mx); ssum += p_[jj]; }
        ssum += __shfl_xor(ssum, 16);
        ssum += __shfl_xor(ssum, 32);
        const float inv = __builtin_amdgcn_rcpf(ssum);

        half4v bfrag;   // B[k=j=quad*4+jj][n=i=m] = attn[i][j]
        #pragma unroll
        for (int jj = 0; jj < 4; ++jj) bfrag[jj] = (_Float16)(p_[jj] * inv);

        float4v zp[2];
        __builtin_amdgcn_s_setprio(1);
        #pragma unroll
        for (int p = 0; p < 2; ++p) {
            float4v ct = hpt[2 * h + p];       // A[m=d'][k=j=quad*4+t]
            half4v afrag;
            #pragma unroll
            for (int t = 0; t < 4; ++t) afrag[t] = (_Float16)ct[t];
            float4v z = (float4v){0.f, 0.f, 0.f, 0.f};
            zp[p] = __builtin_amdgcn_mfma_f32_16x16x16f16(afrag, bfrag, z, 0, 0, 0);
        }
        __builtin_amdgcn_s_setprio(0);
        // elu + pack: lane's g octet (d' = 8*quad + 2t + p), no store needed
        unsigned int w[4];
        #pragma unroll
        for (int t = 0; t < 4; ++t) {
            float x0 = zp[0][t];
            x0 = (x0 > 0.f) ? x0 : (__expf(x0) - 1.f);
            float x1 = zp[1][t];
            x1 = (x1 > 0.f) ? x1 : (__expf(x1) - 1.f);
            w[t] = cvtpk(x0, x1);
        }
        short8 gfrag;
        __builtin_memcpy(&gfrag, w, 16);

        // contraction: C[M=el][N=agent] = sum_d' W2[el][d'] * g[d'][agent]
        __builtin_amdgcn_s_setprio(1);
        #pragma unroll
        for (int H = 0; H < 2; ++H) {
            float4v z = (float4v){0.f, 0.f, 0.f, 0.f};
            z = __builtin_amdgcn_mfma_f32_16x16x32_bf16(wfr[h * 2 + H], gfrag, z, 0, 0, 0);
            #pragma unroll
            for (int reg = 0; reg < 4; ++reg)
                Sacc[H][reg] += fabsf(z[reg]);
        }
        __builtin_amdgcn_s_setprio(0);
    }

    // ---- epilogue: qs, n-reduce, b1+elu+wf, e-sum, single write ----
    float local = 0.f;
    #pragma unroll
    for (int H = 0; H < 2; ++H) {
        float sn[4];
        #pragma unroll
        for (int reg = 0; reg < 4; ++reg) sn[reg] = Sacc[H][reg] * qs_m;
        #pragma unroll
        for (int mask = 1; mask <= 8; mask <<= 1) {
            #pragma unroll
            for (int reg = 0; reg < 4; ++reg) sn[reg] += __shfl_xor(sn[reg], mask);
        }
        // e = H*16 + quad*4 + reg
        float4 b4 = *(const float4*)&b1v[(size_t)b * 32 + H * 16 + quad * 4];
        float4 w4 = *(const float4*)&wfv[(size_t)b * 32 + H * 16 + quad * 4];
        float bq[4] = {b4.x, b4.y, b4.z, b4.w};
        float wq[4] = {w4.x, w4.y, w4.z, w4.w};
        #pragma unroll
        for (int reg = 0; reg < 4; ++reg) {
            float hid = 0.25f * sn[reg] + bq[reg];
            hid = (hid > 0.f) ? hid : expm1f(hid);
            local = fmaf(hid, wq[reg], local);
        }
    }
    local += __shfl_xor(local, 16);
    local += __shfl_xor(local, 32);
    if (lane == 0) out[b] = out[b] + local;   // seed v already in out
}

// ---------------------------------------------------------------------------
extern "C" void kernel_launch(void* const* d_in, const int* in_sizes, int n_in,
                              void* d_out, int out_size, void* d_ws, size_t ws_size,
                              hipStream_t stream)
{
    const float* agent_qs      = (const float*)d_in[0];
    const float* states        = (const float*)d_in[1];
    const float* hidden_states = (const float*)d_in[2];
    const float* uncertainty   = (const float*)d_in[3];
    const float* W_gat         = (const float*)d_in[4];
    const float* att_a         = (const float*)d_in[5];
    const float* w1s_W         = (const float*)d_in[6];
    const float* w1s_b         = (const float*)d_in[7];
    const float* b1_W          = (const float*)d_in[8];
    const float* b1_b          = (const float*)d_in[9];
    const float* wf_W          = (const float*)d_in[10];
    const float* wf_b          = (const float*)d_in[11];
    const float* V1_W          = (const float*)d_in[12];
    const float* V1_b          = (const float*)d_in[13];
    const float* V2_W          = (const float*)d_in[14];
    const float* V2_b          = (const float*)d_in[15];

    char* w = (char*)d_ws;
    unsigned short* w1sTf   = (unsigned short*)w;  w += (size_t)524288 * 2;
    unsigned short* WgTf    = (unsigned short*)w;  w += (size_t)9216 * 2;
    unsigned short* W2      = (unsigned short*)w;  w += (size_t)16777216 * 2;
    float* b1v              = (float*)w;           w += (size_t)131072 * 4;
    float* wfv              = (float*)w;           w += (size_t)131072 * 4;
    float* out              = (float*)d_out;

    k0_pack<<<256, 256, 0, stream>>>(w1s_W, w1sTf);

    kB_fused<<<2113, 256, 0, stream>>>(w1s_W, W_gat, att_a, states, uncertainty,
                                       w1s_b, w1sTf, b1_W, b1_b, wf_W, wf_b,
                                       V1_W, V1_b, V2_W, V2_b,
                                       WgTf, W2, b1v, wfv, out);

    k1_gatmix<<<1024, 256, 0, stream>>>(hidden_states, WgTf, W2, agent_qs,
                                        b1v, wfv, out);
}

// Round 7
// 125.454 us; speedup vs baseline: 1.1950x; 1.1950x over previous
//
#include <hip/hip_runtime.h>
#include <hip/hip_bf16.h>
#include <math.h>

// N_AGENTS=16, RNN_H=64, N_HEADS=4, GAT_D=32, EMB=32, SDIM=128, B=4096 rows

typedef __attribute__((ext_vector_type(8))) short short8;
typedef __attribute__((ext_vector_type(8))) unsigned short ushort8;
typedef __attribute__((ext_vector_type(4))) float float4v;
typedef __attribute__((ext_vector_type(4))) _Float16 half4v;

static __device__ inline unsigned short f2bf(float f) {
    unsigned int x;
    __builtin_memcpy(&x, &f, 4);
    unsigned int r = x + 0x7fffu + ((x >> 16) & 1u);   // RNE
    return (unsigned short)(r >> 16);
}

// packed f32x2 -> bf16x2 (v_cvt_pk_bf16_f32, RNE)
static __device__ inline unsigned int cvtpk(float lo, float hi) {
    __hip_bfloat162 h = __float22bfloat162_rn(make_float2(lo, hi));
    unsigned int u;
    __builtin_memcpy(&u, &h, 4);
    return u;
}

static __device__ inline short8 pack8(float4 f0, float4 f1) {
    unsigned int u[4] = {cvtpk(f0.x, f0.y), cvtpk(f0.z, f0.w),
                         cvtpk(f1.x, f1.y), cvtpk(f1.z, f1.w)};
    short8 s;
    __builtin_memcpy(&s, u, 16);
    return s;
}

// ---------------------------------------------------------------------------
// K0: prep + batched small GEMVs.  (round-3 champion, verbatim)
// ---------------------------------------------------------------------------
__global__ __launch_bounds__(256) void k0_prep(
    const float* __restrict__ w1s_W,     // [129][4096]
    const float* __restrict__ W_gat,     // [64][128]
    const float* __restrict__ att_a,     // [4][64]
    const float* __restrict__ states,    // [4096][128]
    const float* __restrict__ b1_W, const float* __restrict__ b1_b,
    const float* __restrict__ wf_W, const float* __restrict__ wf_b,
    const float* __restrict__ V1_W, const float* __restrict__ V1_b,
    const float* __restrict__ V2_W, const float* __restrict__ V2_b,
    unsigned short* __restrict__ w1sTf,  // [256 tiles][2048] bf16 frag-major
    unsigned short* __restrict__ WgTf,   // [9 tiles][1024] bf16 frag-major
    unsigned short* __restrict__ Sbf,    // [4096][128] bf16 (frag octets)
    float* __restrict__ b1v, float* __restrict__ wfv,
    float* __restrict__ out)             // seeded with v
{
    __shared__ __align__(16) char SMEM[26112];
    const int tid = threadIdx.x, bx = blockIdx.x;

    if (bx < 256) {
        unsigned short* T = (unsigned short*)SMEM;    // [16 cols][136]
        const int c0 = bx * 16;
        const int cc = tid & 15, kr = tid >> 4;
        #pragma unroll
        for (int t = 0; t < 8; ++t) {
            int k = t * 16 + kr;
            T[cc * 136 + k] = f2bf(w1s_W[(size_t)k * 4096 + c0 + cc]);
        }
        __syncthreads();
        const int ks = tid >> 6, q = (tid >> 4) & 3, mm = tid & 15;
        *(ushort8*)&w1sTf[(size_t)bx * 2048 + tid * 8] =
            *(const ushort8*)&T[mm * 136 + ks * 32 + q * 8];
    } else if (bx == 256) {
        unsigned short* T = (unsigned short*)SMEM;    // [128 cols][72]
        #pragma unroll
        for (int t = 0; t < 32; ++t) {
            int i = t * 256 + tid;
            int k = i >> 7, c = i & 127;
            T[c * 72 + k] = f2bf(W_gat[k * 128 + c]);
        }
        __syncthreads();
        #pragma unroll
        for (int t = 0; t < 4; ++t) {
            int i = t * 256 + tid;            // < 1024 ushort8 groups
            int nt = i >> 7, w = i & 127;
            int kh = w >> 6, q = (w >> 4) & 3, mm = w & 15;
            *(ushort8*)&WgTf[nt * 1024 + w * 8] =
                *(const ushort8*)&T[(nt * 16 + mm) * 72 + kh * 32 + q * 8];
        }
        // tile 8: fused attention projections (m = h: src, m = 4+h: dst)
        {
            const int k = tid >> 2, h = tid & 3;
            float ss = 0.f, dd = 0.f;
            #pragma unroll
            for (int d = 0; d < 32; ++d) {
                float wv = W_gat[k * 128 + h * 32 + d];
                ss = fmaf(wv, att_a[h * 64 + d], ss);
                dd = fmaf(wv, att_a[h * 64 + 32 + d], dd);
            }
            const int base = 8192 + (k >> 5) * 512 + ((k >> 3) & 3) * 128 + (k & 7);
            WgTf[base + h * 8]       = f2bf(ss);
            WgTf[base + (4 + h) * 8] = f2bf(dd);
        }
        #pragma unroll
        for (int t = 0; t < 2; ++t) {         // zero cols m = 8..15
            int i = t * 256 + tid;            // < 512
            int kh = i >> 8, q = (i >> 6) & 3, mm = 8 + ((i >> 3) & 7), j = i & 7;
            WgTf[8192 + kh * 512 + q * 128 + mm * 8 + j] = 0;
        }
    } else {
        // ---- MFMA GEMV block: 64 rows, 4 waves x 16 rows ----
        unsigned short* WLu = (unsigned short*)SMEM;  // bf16 [3][128][34]
        for (int i = tid; i < 12288; i += 256) {
            float v = (i < 4096) ? b1_W[i] : (i < 8192 ? wf_W[i - 4096] : V1_W[i - 8192]);
            int set = i >> 12, k = (i >> 5) & 127, e = i & 31;
            WLu[set * 4352 + k * 34 + e] = f2bf(v);
        }
        __syncthreads();

        const int wave = tid >> 6, lane = tid & 63, mm = lane & 15, q = lane >> 4;
        const int b0w = (bx - 257) * 64 + wave * 16;

        short8 a[4];
        #pragma unroll
        for (int ks = 0; ks < 4; ++ks) {
            const float* sp = states + (size_t)(b0w + mm) * 128 + ks * 32 + q * 8;
            a[ks] = pack8(*(const float4*)sp, *(const float4*)(sp + 4));
        }
        // export packed states frags for k2a
        #pragma unroll
        for (int ks = 0; ks < 4; ++ks)
            *(short8*)&Sbf[(size_t)(b0w + mm) * 128 + ks * 32 + q * 8] = a[ks];

        float4v accT[6];
        #pragma unroll
        for (int nt = 0; nt < 6; ++nt) accT[nt] = (float4v){0.f, 0.f, 0.f, 0.f};
        #pragma unroll
        for (int nt = 0; nt < 6; ++nt) {
            const int set = nt >> 1, e = (nt & 1) * 16 + mm;
            #pragma unroll
            for (int ks = 0; ks < 4; ++ks) {
                ushort8 bfu;
                #pragma unroll
                for (int j = 0; j < 8; ++j)
                    bfu[j] = WLu[set * 4352 + (ks * 32 + q * 8 + j) * 34 + e];
                short8 bf;
                __builtin_memcpy(&bf, &bfu, 16);
                accT[nt] = __builtin_amdgcn_mfma_f32_16x16x32_bf16(a[ks], bf, accT[nt], 0, 0, 0);
            }
        }
        float vsum[4] = {0.f, 0.f, 0.f, 0.f};
        #pragma unroll
        for (int p = 0; p < 2; ++p) {
            const int e = p * 16 + mm;
            const float bb1 = b1_b[e], bwf = wf_b[e], bv1 = V1_b[e], v2 = V2_W[e];
            #pragma unroll
            for (int reg = 0; reg < 4; ++reg) {
                const int row = b0w + q * 4 + reg;
                b1v[(size_t)row * 32 + e] = accT[p][reg] + bb1;
                wfv[(size_t)row * 32 + e] = fabsf(accT[2 + p][reg] + bwf);
                vsum[reg] += fmaxf(accT[4 + p][reg] + bv1, 0.f) * v2;
            }
        }
        #pragma unroll
        for (int reg = 0; reg < 4; ++reg) {
            vsum[reg] += __shfl_xor(vsum[reg], 1);
            vsum[reg] += __shfl_xor(vsum[reg], 2);
            vsum[reg] += __shfl_xor(vsum[reg], 4);
            vsum[reg] += __shfl_xor(vsum[reg], 8);
        }
        if (mm == 0) {
            #pragma unroll
            for (int reg = 0; reg < 4; ++reg)
                out[b0w + q * 4 + reg] = vsum[reg] + V2_b[0];
        }
    }
}

// ---------------------------------------------------------------------------
// K2a v3: MLP-first streaming GEMM. Block = 64 rows x 8 E's, 4 waves,
// wave = 2 E's. Sbf slab (16KB) staged into LDS ONCE per block (coalesced;
// kills the 128x-per-row L2 re-read: 134MB -> 16MB), 16 A-frag loads
// batched up front (16 outstanding misses under the stage), B-frags from
// conflict-free LDS (stride 136 ushorts: 2-way max = free). One barrier.
// ---------------------------------------------------------------------------
__global__ __launch_bounds__(256) void k2a_gemm(
    const unsigned short* __restrict__ w1sTf,   // [256][2048] frag-major
    const unsigned short* __restrict__ Sbf,     // [4096][128] bf16 frags
    const float* __restrict__ uncertainty,      // [4096]
    const float* __restrict__ w1s_W,            // row 128 used
    const float* __restrict__ w1s_b,
    unsigned short* __restrict__ W2)            // [4096 r][4096 c'] bf16
{
    __shared__ __align__(16) unsigned short Sb[64 * 136];   // 17408 B
    const int bx = blockIdx.x;
    const int rb = bx >> 4, pg = bx & 15;       // 64 row-blocks x 16 col-grps
    const int tid = threadIdx.x;
    const int wave = tid >> 6, lane = tid & 63;
    const int m = lane & 15, quad = lane >> 4;

    // cooperative stage: 64 rows x 256B, coalesced 64B per thread
    {
        const int row = tid >> 2, seg = tid & 3;
        const unsigned short* src = &Sbf[(size_t)(rb * 64 + row) * 128 + seg * 32];
        #pragma unroll
        for (int k = 0; k < 4; ++k)
            *(ushort8*)&Sb[row * 136 + seg * 32 + k * 8] =
                *(const ushort8*)&src[k * 8];
    }

    const int E0 = pg * 8 + wave * 2;           // wave owns E0, E0+1

    // A-frags: all 16 x 16B issued up front (independent, 16 outstanding)
    short8 A[2][2][4];
    #pragma unroll
    for (int e = 0; e < 2; ++e)
        #pragma unroll
        for (int t = 0; t < 2; ++t)
            #pragma unroll
            for (int ks = 0; ks < 4; ++ks)
                A[e][t][ks] = *(const short8*)&w1sTf[
                    (size_t)((E0 + e) * 2 + t) * 2048 + ks * 512 + lane * 8];

    const float* w128 = w1s_W + (size_t)128 * 4096;
    float wf[2][2][4], bb[2][2][4];
    #pragma unroll
    for (int e = 0; e < 2; ++e)
        #pragma unroll
        for (int t = 0; t < 2; ++t) {
            float4 w4 = *(const float4*)&w128[((E0 + e) * 2 + t) * 16 + quad * 4];
            float4 b4 = *(const float4*)&w1s_b[((E0 + e) * 2 + t) * 16 + quad * 4];
            wf[e][t][0] = w4.x; wf[e][t][1] = w4.y; wf[e][t][2] = w4.z; wf[e][t][3] = w4.w;
            bb[e][t][0] = b4.x; bb[e][t][1] = b4.y; bb[e][t][2] = b4.z; bb[e][t][3] = b4.w;
        }

    __syncthreads();

    #pragma unroll
    for (int c = 0; c < 4; ++c) {
        const int lr = c * 16 + m;              // local row
        const float us = uncertainty[rb * 64 + lr];
        short8 Bf[4];
        #pragma unroll
        for (int ks = 0; ks < 4; ++ks)
            Bf[ks] = *(const short8*)&Sb[lr * 136 + ks * 32 + quad * 8];

        float4v z[2][2];
        #pragma unroll
        for (int e = 0; e < 2; ++e)
            #pragma unroll
            for (int t = 0; t < 2; ++t)
                z[e][t] = (float4v){0.f, 0.f, 0.f, 0.f};
        #pragma unroll
        for (int ks = 0; ks < 4; ++ks)
            #pragma unroll
            for (int e = 0; e < 2; ++e)
                #pragma unroll
                for (int t = 0; t < 2; ++t)
                    z[e][t] = __builtin_amdgcn_mfma_f32_16x16x32_bf16(
                        A[e][t][ks], Bf[ks], z[e][t], 0, 0, 0);

        #pragma unroll
        for (int e = 0; e < 2; ++e) {
            const int E = E0 + e;
            unsigned int wpk[4];
            #pragma unroll
            for (int reg = 0; reg < 4; ++reg) {
                float za = z[e][0][reg] + us * wf[e][0][reg] + bb[e][0][reg];
                float zb = z[e][1][reg] + us * wf[e][1][reg] + bb[e][1][reg];
                wpk[reg] = cvtpk(za, zb);        // d' = (2d, 2d+1)
            }
            short8 pk;
            __builtin_memcpy(&pk, wpk, 16);
            const int eo = (E >> 4) * 512 + (E & 15) * 32 + quad * 8;
            *(short8*)&W2[(size_t)(rb * 64 + lr) * 4096 + eo] = pk;
        }
    }
}

// ---------------------------------------------------------------------------
// K1: GAT + contraction + epilogue fused, 1 wave = 1 batch row.
// (round-3 champion, verbatim)
// ---------------------------------------------------------------------------
__global__ __launch_bounds__(256) void k1_gatmix(
    const float* __restrict__ hidden_states,  // [4096*16][64] fp32
    const unsigned short* __restrict__ WgTf,  // [9][1024] bf16 frag-major
    const unsigned short* __restrict__ W2,    // [4096][4096] bf16 frag-major
    const float* __restrict__ agent_qs,       // [4096][16]
    const float* __restrict__ b1v, const float* __restrict__ wfv,
    float* __restrict__ out)                  // seeded with v
{
    const int wave = threadIdx.x >> 6;
    const int b = blockIdx.x * 4 + wave;
    const int lane = threadIdx.x & 63, m = lane & 15, quad = lane >> 4;
    __shared__ __align__(16) float sc[4 * 320];   // per-wave scratch, 5KB
    float* scr = &sc[wave * 320];

    // prefetch W2 A-frags (i = h*2+H), hidden under GAT compute
    short8 wfr[8];
    #pragma unroll
    for (int i = 0; i < 8; ++i)
        wfr[i] = *(const short8*)&W2[(size_t)b * 4096 + i * 512 + m * 32 + quad * 8];
    const float qs_m = agent_qs[b * 16 + m];

    // ---- MFMA1: 8 hp tiles + proj tile ----
    const float* hrow = hidden_states + ((size_t)b * 16 + m) * 64;
    float4 f0 = *(const float4*)(hrow + quad * 8);
    float4 f1 = *(const float4*)(hrow + quad * 8 + 4);
    short8 a0 = pack8(f0, f1);
    f0 = *(const float4*)(hrow + 32 + quad * 8);
    f1 = *(const float4*)(hrow + 32 + quad * 8 + 4);
    short8 a1 = pack8(f0, f1);

    float4v hpt[9];
    #pragma unroll
    for (int nt = 0; nt < 9; ++nt) {
        short8 bf0 = *(const short8*)&WgTf[nt * 1024 + lane * 8];
        short8 bf1 = *(const short8*)&WgTf[nt * 1024 + 512 + lane * 8];
        float4v z = (float4v){0.f, 0.f, 0.f, 0.f};
        z = __builtin_amdgcn_mfma_f32_16x16x32_bf16(a0, bf0, z, 0, 0, 0);
        z = __builtin_amdgcn_mfma_f32_16x16x32_bf16(a1, bf1, z, 0, 0, 0);
        hpt[nt] = z;
    }

    // stash proj tile transposed: scr[col*20 + row]
    {
        float4 pr = {hpt[8][0], hpt[8][1], hpt[8][2], hpt[8][3]};
        *(float4*)&scr[m * 20 + quad * 4] = pr;
    }

    float Sacc[2][4] = {};

    // ---- per head: softmax + PV MFMA + in-register contraction ----
    #pragma unroll
    for (int h = 0; h < 4; ++h) {
        const float src_m = scr[h * 20 + m];                        // src[i=m]
        float4 pdv = *(const float4*)&scr[(4 + h) * 20 + quad * 4]; // dst[j]
        float pd[4] = {pdv.x, pdv.y, pdv.z, pdv.w};

        float e_[4];
        #pragma unroll
        for (int jj = 0; jj < 4; ++jj) {
            float x = src_m + pd[jj];
            e_[jj] = fmaxf(x, 0.2f * x);       // leaky_relu(0.2)
        }
        float mx = fmaxf(fmaxf(e_[0], e_[1]), fmaxf(e_[2], e_[3]));
        mx = fmaxf(mx, __shfl_xor(mx, 16));
        mx = fmaxf(mx, __shfl_xor(mx, 32));
        float p_[4], ssum = 0.f;
        #pragma unroll
        for (int jj = 0; jj < 4; ++jj) { p_[jj] = __expf(e_[jj] - mx); ssum += p_[jj]; }
        ssum += __shfl_xor(ssum, 16);
        ssum += __shfl_xor(ssum, 32);
        const float inv = __builtin_amdgcn_rcpf(ssum);

        half4v bfrag;   // B[k=j=quad*4+jj][n=i=m] = attn[i][j]
        #pragma unroll
        for (int jj = 0; jj < 4; ++jj) bfrag[jj] = (_Float16)(p_[jj] * inv);

        float4v zp[2];
        #pragma unroll
        for (int p = 0; p < 2; ++p) {
            float4v ct = hpt[2 * h + p];       // A[m=d'][k=j=quad*4+t]
            half4v afrag;
            #pragma unroll
            for (int t = 0; t < 4; ++t) afrag[t] = (_Float16)ct[t];
            float4v z = (float4v){0.f, 0.f, 0.f, 0.f};
            zp[p] = __builtin_amdgcn_mfma_f32_16x16x16f16(afrag, bfrag, z, 0, 0, 0);
        }
        // elu + pack: lane's g octet (d' = 8*quad + 2t + p), no store needed
        unsigned int w[4];
        #pragma unroll
        for (int t = 0; t < 4; ++t) {
            float x0 = zp[0][t];
            x0 = (x0 > 0.f) ? x0 : (__expf(x0) - 1.f);
            float x1 = zp[1][t];
            x1 = (x1 > 0.f) ? x1 : (__expf(x1) - 1.f);
            w[t] = cvtpk(x0, x1);
        }
        short8 gfrag;
        __builtin_memcpy(&gfrag, w, 16);

        // contraction: C[M=el][N=agent] = sum_d' W2[el][d'] * g[d'][agent]
        #pragma unroll
        for (int H = 0; H < 2; ++H) {
            float4v z = (float4v){0.f, 0.f, 0.f, 0.f};
            z = __builtin_amdgcn_mfma_f32_16x16x32_bf16(wfr[h * 2 + H], gfrag, z, 0, 0, 0);
            #pragma unroll
            for (int reg = 0; reg < 4; ++reg)
                Sacc[H][reg] += fabsf(z[reg]);
        }
    }

    // ---- epilogue: qs, n-reduce, b1+elu+wf, e-sum, single write ----
    float local = 0.f;
    #pragma unroll
    for (int H = 0; H < 2; ++H) {
        float sn[4];
        #pragma unroll
        for (int reg = 0; reg < 4; ++reg) sn[reg] = Sacc[H][reg] * qs_m;
        #pragma unroll
        for (int mask = 1; mask <= 8; mask <<= 1) {
            #pragma unroll
            for (int reg = 0; reg < 4; ++reg) sn[reg] += __shfl_xor(sn[reg], mask);
        }
        // e = H*16 + quad*4 + reg
        float4 b4 = *(const float4*)&b1v[(size_t)b * 32 + H * 16 + quad * 4];
        float4 w4 = *(const float4*)&wfv[(size_t)b * 32 + H * 16 + quad * 4];
        float bq[4] = {b4.x, b4.y, b4.z, b4.w};
        float wq[4] = {w4.x, w4.y, w4.z, w4.w};
        #pragma unroll
        for (int reg = 0; reg < 4; ++reg) {
            float hid = 0.25f * sn[reg] + bq[reg];
            hid = (hid > 0.f) ? hid : expm1f(hid);
            local = fmaf(hid, wq[reg], local);
        }
    }
    local += __shfl_xor(local, 16);
    local += __shfl_xor(local, 32);
    if (lane == 0) out[b] = out[b] + local;   // seed v already in out
}

// ---------------------------------------------------------------------------
extern "C" void kernel_launch(void* const* d_in, const int* in_sizes, int n_in,
                              void* d_out, int out_size, void* d_ws, size_t ws_size,
                              hipStream_t stream)
{
    const float* agent_qs      = (const float*)d_in[0];
    const float* states        = (const float*)d_in[1];
    const float* hidden_states = (const float*)d_in[2];
    const float* uncertainty   = (const float*)d_in[3];
    const float* W_gat         = (const float*)d_in[4];
    const float* att_a         = (const float*)d_in[5];
    const float* w1s_W         = (const float*)d_in[6];
    const float* w1s_b         = (const float*)d_in[7];
    const float* b1_W          = (const float*)d_in[8];
    const float* b1_b          = (const float*)d_in[9];
    const float* wf_W          = (const float*)d_in[10];
    const float* wf_b          = (const float*)d_in[11];
    const float* V1_W          = (const float*)d_in[12];
    const float* V1_b          = (const float*)d_in[13];
    const float* V2_W          = (const float*)d_in[14];
    const float* V2_b          = (const float*)d_in[15];

    char* w = (char*)d_ws;
    unsigned short* w1sTf   = (unsigned short*)w;  w += (size_t)524288 * 2;
    unsigned short* WgTf    = (unsigned short*)w;  w += (size_t)9216 * 2;
    unsigned short* Sbf     = (unsigned short*)w;  w += (size_t)524288 * 2;
    unsigned short* W2      = (unsigned short*)w;  w += (size_t)16777216 * 2;
    float* b1v              = (float*)w;           w += (size_t)131072 * 4;
    float* wfv              = (float*)w;           w += (size_t)131072 * 4;
    float* out              = (float*)d_out;

    k0_prep<<<321, 256, 0, stream>>>(w1s_W, W_gat, att_a, states,
                                     b1_W, b1_b, wf_W, wf_b, V1_W, V1_b,
                                     V2_W, V2_b, w1sTf, WgTf, Sbf, b1v, wfv, out);

    k2a_gemm<<<1024, 256, 0, stream>>>(w1sTf, Sbf, uncertainty, w1s_W, w1s_b, W2);

    k1_gatmix<<<1024, 256, 0, stream>>>(hidden_states, WgTf, W2, agent_qs,
                                        b1v, wfv, out);
}